// Round 13
// baseline (181.658 us; speedup 1.0000x reference)
//
#include <hip/hip_runtime.h>

// ---------------- problem constants ----------------
constexpr int B_ = 2, H_ = 512, W_ = 512;
constexpr int HWl = H_ * W_;          // 262144
constexpr int TOT = B_ * HWl;         // 524288
constexpr int KC = 200;               // TOP_K_INSTANCE
constexpr int NBLK = 256;             // k_nms blocks (128 row-tiles x 2 batches)
constexpr int GRID = 512;             // k_mega blocks
constexpr int BINOFF = 0x3DCCC;       // (bits(0.1f))>>12 : floor of thresholded values
constexpr float INV2S2 = 0.0078125f;  // 1/128, exact power of 2

// output layout (flat float32, concatenated in return order)
constexpr int OUT_CENTER = 0;                 // [B,1,H,W]
constexpr int OUT_OFF = TOT;                  // [B,2,H,W]
constexpr int OUT_CW = 3 * TOT;               // [B,H,W] ones
constexpr int OUT_OW = 4 * TOT;               // [B,H,W] fg

__device__ __forceinline__ float hwthr(float v) { return v > 0.1f ? v : -1.0f; }
__device__ __forceinline__ float4 max4(float4 a, float4 b) {
  return make_float4(fmaxf(a.x, b.x), fmaxf(a.y, b.y), fmaxf(a.z, b.z), fmaxf(a.w, b.w));
}
// monotone fine bin on value bits [31:12]; ~260 peaks max per bin
__device__ __forceinline__ int finebin(unsigned long long kk) {
  int bq = (int)(kk >> 44) - BINOFF;            // key32>>12 - offset
  return bq < 0 ? 0 : (bq > 8191 ? 8191 : bq);
}

// device-wide barrier: all GRID blocks co-resident (launch_bounds guarantees
// >=4 blocks/CU capacity; 256 CUs * 4 = 1024 >= 512). Device-scope atomics
// bypass the non-coherent per-XCD L2s.
__device__ __forceinline__ void gridbar(int* cnt, int target) {
  __threadfence();            // every thread flushes its own prior writes
  __syncthreads();
  if (threadIdx.x == 0) {
    __hip_atomic_fetch_add(cnt, 1, __ATOMIC_ACQ_REL, __HIP_MEMORY_SCOPE_AGENT);
    while (__hip_atomic_load(cnt, __ATOMIC_ACQUIRE, __HIP_MEMORY_SCOPE_AGENT) < target) {
      __builtin_amdgcn_s_sleep(8);
    }
  }
  __syncthreads();
}

// ---------------- kernels ----------------

// fused threshold + separable 7x7 NMS, LDS-tiled (4 output rows + 3-row halo).
// Peaks staged in LDS -> per-block key segment (plain bcount store).
__global__ __launch_bounds__(256) void k_nms(const float* __restrict__ ctr,
                                             unsigned long long* __restrict__ keys,
                                             int* __restrict__ bcount) {
  __shared__ float rmx[10 * 512];
  __shared__ unsigned long long lkeys[1024];
  __shared__ int lnum;
  int tid = threadIdx.x, blk = blockIdx.x;     // NBLK blocks
  int b = blk >> 7, y0 = (blk & 127) << 2;     // output rows y0..y0+3
  if (tid == 0) lnum = 0;
  const float4* c4p = (const float4*)(ctr + b * HWl);
  // horizontal 7-max of thresholded heatmap for rows y0-3 .. y0+6
  for (int u = tid; u < 1280; u += 256) {
    int r = u >> 7, c4 = u & 127, gy = y0 - 3 + r;
    float4 m = make_float4(-1e30f, -1e30f, -1e30f, -1e30f);
    if (gy >= 0 && gy < H_) {
      float4 v = c4p[gy * 128 + c4];
      float4 L = make_float4(-1e30f, -1e30f, -1e30f, -1e30f), R = L;
      if (c4 > 0) L = c4p[gy * 128 + c4 - 1];
      if (c4 < 127) R = c4p[gy * 128 + c4 + 1];
      float a1 = hwthr(L.y), a2 = hwthr(L.z), a3 = hwthr(L.w);
      float a4 = hwthr(v.x), a5 = hwthr(v.y), a6 = hwthr(v.z), a7 = hwthr(v.w);
      float a8 = hwthr(R.x), a9 = hwthr(R.y), a10 = hwthr(R.z);
      float core = fmaxf(fmaxf(a4, a5), fmaxf(a6, a7));
      m.x = fmaxf(fmaxf(a1, a2), fmaxf(a3, core));
      m.y = fmaxf(fmaxf(a2, a3), fmaxf(core, a8));
      m.z = fmaxf(fmaxf(a3, core), fmaxf(a8, a9));
      m.w = fmaxf(fmaxf(core, a8), fmaxf(a9, a10));
    }
    ((float4*)rmx)[u] = m;
  }
  __syncthreads();
  // vertical 7-max + peak emit
  for (int u = tid; u < 512; u += 256) {
    int orr = u >> 7, c4 = u & 127;
    int y = y0 + orr;
    float4 pool = ((float4*)rmx)[orr * 128 + c4];
#pragma unroll
    for (int r = 1; r <= 6; ++r)
      pool = max4(pool, ((float4*)rmx)[(orr + r) * 128 + c4]);
    float4 v = c4p[y * 128 + c4];
    float vv[4] = {v.x, v.y, v.z, v.w};
    float pv[4] = {pool.x, pool.y, pool.z, pool.w};
#pragma unroll
    for (int j = 0; j < 4; ++j) {
      float vj = vv[j];
      if (vj > 0.1f && vj == pv[j]) {  // exact equality, same as reference hmp==pooled
        unsigned int i = (unsigned int)(b * HWl + y * W_ + c4 * 4 + j);
        unsigned long long comp = ((unsigned long long)__float_as_uint(vj) << 32)
                                | (unsigned long long)(0xFFFFFFFFu - i);
        int slot = atomicAdd(&lnum, 1);  // LDS atomic, cheap
        if (slot < 1024) lkeys[slot] = comp;
      }
    }
  }
  __syncthreads();
  int n = lnum; if (n > 1024) n = 1024;
  if (tid == 0) bcount[blk] = n;
  for (int q = tid; q < n; q += 256) keys[blk * 1024 + q] = lkeys[q];
}

// single selection kernel: LDS fine histogram from L2-hot keys, suffix scan ->
// P1, filtered second pass (survivors < 1024), exact rank by 64-bit comparison
// (unique keys -> (value desc, index asc) order). Also zeroes barrier counters.
__global__ __launch_bounds__(1024) void k_sel(
    const unsigned long long* __restrict__ keys, const int* __restrict__ bcount,
    float* __restrict__ cand_val, int* __restrict__ cand_bid,
    int* __restrict__ cand_cy, int* __restrict__ cand_cx,
    int* __restrict__ barcnt) {
  __shared__ int hist[8192];          // 32 KB
  __shared__ int sfx[1024];
  __shared__ int bc[NBLK];
  __shared__ int s_P1, ln;
  __shared__ unsigned long long wk[1024];
  int tid = threadIdx.x;
  if (tid == 0) { s_P1 = 0; ln = 0; }
  if (tid < 2) barcnt[tid] = 0;       // re-arm k_mega's barriers every call
  if (tid < NBLK) { int c = bcount[tid]; bc[tid] = c > 1024 ? 1024 : c; }
  for (int q = tid; q < 8192; q += 1024) hist[q] = 0;
  __syncthreads();
  // ---- build LDS hist: 4 threads/segment, ~11 L2-hot loads each ----
  int seg = tid >> 2, sub = tid & 3;
  int nn = bc[seg];
  for (int q = sub; q < nn; q += 4)
    atomicAdd(&hist[finebin(keys[seg * 1024 + q])], 1);
  __syncthreads();
  // ---- suffix scan (8 bins/thread) -> P1 ----
  int bins[8];
  int cs = 0;
#pragma unroll
  for (int q = 0; q < 8; ++q) { bins[q] = hist[tid * 8 + q]; cs += bins[q]; }
  sfx[tid] = cs;
  __syncthreads();
  for (int off = 1; off < 1024; off <<= 1) {
    int v = (tid + off < 1024) ? sfx[tid + off] : 0;
    __syncthreads();
    sfx[tid] += v;
    __syncthreads();
  }
  int total = sfx[0];
  if (total > KC) {
    int above = (tid == 1023) ? 0 : sfx[tid + 1];
    if (sfx[tid] >= KC && above < KC) {
      int acc = above;
#pragma unroll
      for (int bq = 7; bq >= 0; --bq) {
        acc += bins[bq];
        if (acc >= KC) { s_P1 = tid * 8 + bq; break; }
      }
    }
  }
  __syncthreads();
  int P1 = s_P1;
  // ---- filter all segments (second L2-hot pass) ----
  for (int q = sub; q < nn; q += 4) {
    unsigned long long kk = keys[seg * 1024 + q];
    if (finebin(kk) >= P1) {
      int w2 = atomicAdd(&ln, 1);
      if (w2 < 1024) wk[w2] = kk;
    }
  }
  __syncthreads();
  int n = ln > 1024 ? 1024 : ln;
  // ---- exact rank by comparison (keys unique -> unique ranks) ----
  if (tid < n) {
    unsigned long long mine = wk[tid];
    int r = 0;
    for (int j = 0; j < n; ++j) r += (wk[j] > mine) ? 1 : 0;
    if (r < KC) {
      unsigned int key32 = (unsigned int)(mine >> 32);
      unsigned int idx = 0xFFFFFFFFu - (unsigned int)(mine & 0xFFFFFFFFULL);
      int bb = (int)(idx >> 18), rem = (int)(idx & (HWl - 1));
      cand_val[r] = __uint_as_float(key32);
      cand_bid[r] = bb; cand_cy[r] = rem >> 9; cand_cx[r] = rem & (W_ - 1);
    }
  }
  if (tid >= n && tid < KC) {  // unfilled slots (only when n < KC)
    cand_val[tid] = -1e30f; cand_bid[tid] = 0; cand_cy[tid] = 0; cand_cx[tid] = 0;
  }
}

// mega-kernel: phase A (wsum+select, blocks<KC; block 0 zeroes sums) ->
// grid barrier -> phase B (center-list build, argmin, splat, sum accumulate;
// ins kept in registers) -> grid barrier -> phase C (offsets + weights).
__global__ __launch_bounds__(256, 2) void k_mega(
    const float* __restrict__ offs, const int* __restrict__ sem,
    const float* __restrict__ mix,
    const float* __restrict__ cand_val, const int* __restrict__ cand_bid,
    const int* __restrict__ cand_cy, const int* __restrict__ cand_cx,
    int* __restrict__ selected,
    int* __restrict__ gsy, int* __restrict__ gsx, int* __restrict__ gcn,
    int* __restrict__ barcnt, float* __restrict__ out) {
  __shared__ float4 sc[KC];
  __shared__ float2 gl[KC];
  __shared__ int lsy[KC + 1], lsx[KC + 1], lcn[KC + 1];
  __shared__ int ssum[256];
  __shared__ int wtot[4];
  __shared__ int gcnt_s;
  int tid = threadIdx.x, blk = blockIdx.x;

  // ================= phase A: window-sum + select (blocks < KC) =================
  if (blk == 0) {
    for (int q = tid; q < 3 * (KC + 1) * B_; q += 256) gsy[q] = 0;  // gsy|gsx|gcn contiguous
  }
  if (blk < KC) {
    int k = blk;
    int cb = cand_bid[k], cy = cand_cy[k], cx = cand_cx[k];
    float v = cand_val[k];
    int wy0 = cy - 25; if (wy0 < 0) wy0 = 0;
    int wy1 = cy + 26; if (wy1 > H_) wy1 = H_;
    int wx0 = cx - 25; if (wx0 < 0) wx0 = 0;
    int wx1 = cx + 26; if (wx1 > W_) wx1 = W_;
    int wd = wx1 - wx0, nr = wy1 - wy0;         // both <= 51
    int wave = tid >> 6, lane = tid & 63;
    int s = 0;
    for (int rr = wave; rr < nr; rr += 4) {
      if (lane < wd) {
        int sv = sem[cb * HWl + (wy0 + rr) * W_ + wx0 + lane];
        s += (sv >= 11 && sv <= 18) ? 1 : 0;
      }
    }
    ssum[tid] = s;
    __syncthreads();
    for (int o = 128; o > 0; o >>= 1) {
      if (tid < o) ssum[tid] += ssum[tid + o];
      __syncthreads();
    }
    if (tid == 0) {
      bool sel = (v >= 0.1f) && (mix[cb * HWl + cy * W_ + cx] < 0.5f) && (ssum[0] >= 64);
      selected[k] = sel ? 1 : 0;
    }
  }
  gridbar(barcnt + 0, GRID);

  // ================= phase B: fused argmin + splat + accumulate =================
  int t = blk * 256 + tid;          // t < 131072
  int p = t << 2;
  int b = p >> 18;                  // uniform per block
  int rem = p & (HWl - 1), y = rem >> 9, x0i = rem & (W_ - 1);
  int yA = (int)(((unsigned)(blk * 1024) & (HWl - 1)) >> 9);  // block's first row

  for (int q = tid; q <= KC; q += 256) { lsy[q] = 0; lsx[q] = 0; lcn[q] = 0; }
  if (tid == 0) gcnt_s = 0;
  // ---- build this batch's packed center list (rank order preserved) ----
  // selected[] is intra-kernel cross-block data: agent-scope atomic load
  // (bypasses potentially-stale per-XCD L2 lines from prior graph replays).
  bool sel = false; int cb = 0, ccy = 0, ccx = 0;
  if (tid < KC) {
    sel = __hip_atomic_load(&selected[tid], __ATOMIC_RELAXED, __HIP_MEMORY_SCOPE_AGENT) != 0;
    cb = cand_bid[tid]; ccy = cand_cy[tid]; ccx = cand_cx[tid];
  }
  bool mine = sel && (cb == b);
  unsigned long long mk = __ballot(mine);
  int lane = tid & 63, wv = tid >> 6;
  if (lane == 0) wtot[wv] = __popcll(mk);
  __syncthreads();
  int base = 0;
  for (int w2 = 0; w2 < wv; ++w2) base += wtot[w2];
  int S = wtot[0] + wtot[1] + wtot[2] + wtot[3];
  if (mine) {
    int pos = base + __popcll(mk & ((1ULL << lane) - 1ULL));
    float fyc = (float)ccy, fxc = (float)ccx;
    float cc = __fadd_rn(__fmul_rn(fyc, fyc), __fmul_rn(fxc, fxc));
    sc[pos] = make_float4(fyc, fxc, cc, 0.0f);
  }
  __syncthreads();
  // ---- prefilter Gaussian-relevant centers for this block's rows ----
  if (tid < S) {
    float cyv = sc[tid].x;
    if (cyv >= (float)(yA - 25) && cyv <= (float)(yA + 26)) {
      int gp = atomicAdd(&gcnt_s, 1);
      gl[gp] = make_float2(cyv, sc[tid].y);
    }
  }
  __syncthreads();
  int G = gcnt_s;

  float fy = (float)y;
  float4 oy4 = *(const float4*)(offs + b * 2 * HWl + rem);
  float4 ox4 = *(const float4*)(offs + b * 2 * HWl + HWl + rem);
  float oyv[4] = {oy4.x, oy4.y, oy4.z, oy4.w};
  float oxv[4] = {ox4.x, ox4.y, ox4.z, ox4.w};
  float lyv[4], lxv[4], llv[4], bd[4];
  int bsg[4];
#pragma unroll
  for (int j = 0; j < 4; ++j) {
    float fx = (float)(x0i + j);
    // exact op order of reference: ll = ly*ly + lx*lx (no FMA)
    lyv[j] = __fadd_rn(fy, oyv[j]);
    lxv[j] = __fadd_rn(fx, oxv[j]);
    llv[j] = __fadd_rn(__fmul_rn(lyv[j], lyv[j]), __fmul_rn(lxv[j], lxv[j]));
    bd[j] = 3.0e38f; bsg[j] = 0;
  }
  // argmin over all S (exact expanded-quadratic op order; first-min tie-break)
  for (int s = 0; s < S; ++s) {
    float4 c = sc[s];
#pragma unroll
    for (int j = 0; j < 4; ++j) {
      float dot = __fadd_rn(__fmul_rn(c.x, lyv[j]), __fmul_rn(c.y, lxv[j]));
      float d2 = __fadd_rn(__fsub_rn(c.z, __fmul_rn(2.0f, dot)), llv[j]);
      bool better = d2 < bd[j];
      bd[j] = better ? d2 : bd[j];
      bsg[j] = better ? (s + 1) : bsg[j];
    }
  }
  // Gaussian max-splat over prefiltered list (fp max is order-independent)
  float bg[4] = {0.0f, 0.0f, 0.0f, 0.0f};
  for (int g = 0; g < G; ++g) {
    float2 gc = gl[g];
    float dyc = fy - gc.x;
    if (fabsf(dyc) <= 25.0f) {
      float gy = expf(-__fmul_rn(__fmul_rn(dyc, dyc), INV2S2));
#pragma unroll
      for (int j = 0; j < 4; ++j) {
        float dxc = (float)(x0i + j) - gc.y;
        if (fabsf(dxc) <= 25.0f) {
          float gx = expf(-__fmul_rn(__fmul_rn(dxc, dxc), INV2S2));
          bg[j] = fmaxf(bg[j], __fmul_rn(gy, gx));
        }
      }
    }
  }
  *(float4*)(out + OUT_CENTER + p) = make_float4(bg[0], bg[1], bg[2], bg[3]);
  int4 sv4 = *(const int4*)(sem + p);
  int svv[4] = {sv4.x, sv4.y, sv4.z, sv4.w};
  int insv[4];                       // kept in REGISTERS across the barrier
  bool s_any = S > 0;
#pragma unroll
  for (int j = 0; j < 4; ++j) {
    bool thing = (svv[j] >= 11 && svv[j] <= 18);
    insv[j] = (thing && s_any) ? bsg[j] : 0;
  }
  // merged per-thread local-bin accumulation (adjacent px often share a segment)
  int curSeg = -1, aY = 0, aX = 0, aC = 0;
#pragma unroll
  for (int j = 0; j < 4; ++j) {
    if (insv[j] > 0) {
      int sg = insv[j];
      if (sg != curSeg) {
        if (curSeg >= 0) {
          atomicAdd(&lsy[curSeg], aY); atomicAdd(&lsx[curSeg], aX); atomicAdd(&lcn[curSeg], aC);
        }
        curSeg = sg; aY = 0; aX = 0; aC = 0;
      }
      aY += y; aX += x0i + j; aC += 1;
    }
  }
  if (curSeg >= 0) {
    atomicAdd(&lsy[curSeg], aY); atomicAdd(&lsx[curSeg], aX); atomicAdd(&lcn[curSeg], aC);
  }
  __syncthreads();
  for (int q = tid; q <= KC; q += 256) {
    int c = lcn[q];
    if (c) {
      int gq = b * (KC + 1) + q;
      atomicAdd(&gcn[gq], c); atomicAdd(&gsy[gq], lsy[q]); atomicAdd(&gsx[gq], lsx[q]);
    }
  }
  gridbar(barcnt + 1, GRID);

  // ================= phase C: offsets + weights =================
  // cache this batch's completed sums in LDS (agent-scope atomic loads bypass
  // stale per-XCD L2); reuse lsy/lsx/lcn.
  for (int q = tid; q <= KC; q += 256) {
    int gq = b * (KC + 1) + q;
    lsy[q] = __hip_atomic_load(&gsy[gq], __ATOMIC_RELAXED, __HIP_MEMORY_SCOPE_AGENT);
    lsx[q] = __hip_atomic_load(&gsx[gq], __ATOMIC_RELAXED, __HIP_MEMORY_SCOPE_AGENT);
    lcn[q] = __hip_atomic_load(&gcn[gq], __ATOMIC_RELAXED, __HIP_MEMORY_SCOPE_AGENT);
  }
  __syncthreads();
  float oy[4], ox[4], ow[4];
#pragma unroll
  for (int j = 0; j < 4; ++j) {
    if (insv[j] > 0) {
      int sg = insv[j];
      float c = fmaxf((float)lcn[sg], 1.0f);
      oy[j] = __fsub_rn((float)lsy[sg] / c, fy);
      ox[j] = __fsub_rn((float)lsx[sg] / c, (float)(x0i + j));
      ow[j] = 1.0f;
    } else { oy[j] = 0.0f; ox[j] = 0.0f; ow[j] = 0.0f; }
  }
  *(float4*)(out + OUT_OFF + b * 2 * HWl + rem) = make_float4(oy[0], oy[1], oy[2], oy[3]);
  *(float4*)(out + OUT_OFF + b * 2 * HWl + HWl + rem) = make_float4(ox[0], ox[1], ox[2], ox[3]);
  *(float4*)(out + OUT_CW + p) = make_float4(1.0f, 1.0f, 1.0f, 1.0f);
  *(float4*)(out + OUT_OW + p) = make_float4(ow[0], ow[1], ow[2], ow[3]);
}

// ---------------- launch ----------------
extern "C" void kernel_launch(void* const* d_in, const int* in_sizes, int n_in,
                              void* d_out, int out_size, void* d_ws, size_t ws_size,
                              hipStream_t stream) {
  const float* ctr = (const float*)d_in[0];
  const float* offs = (const float*)d_in[1];
  const int* sem = (const int*)d_in[2];
  const float* mix = (const float*)d_in[3];
  float* out = (float*)d_out;

  char* w = (char*)d_ws;
  int* gz = (int*)(w + 0);                              // gsy|gsx|gcn, 3*402 ints
  int* gsy = gz;                                        // [zeroed by k_mega blk 0 phase A]
  int* gsx = gz + (KC + 1) * B_;
  int* gcn = gz + 2 * (KC + 1) * B_;                    // ends 4824
  int* barcnt = (int*)(w + 5120);                       // 2 ints [zeroed by k_sel]
  int* bcount = (int*)(w + 8192);                       // 256 ints, fully rewritten
  float* cand_val = (float*)(w + 10240);
  int* cand_bid = (int*)(w + 11264);
  int* cand_cy = (int*)(w + 12288);
  int* cand_cx = (int*)(w + 13312);
  int* selected = (int*)(w + 14336);
  unsigned long long* keys = (unsigned long long*)(w + 65536);   // 2 MB

  k_nms<<<NBLK, 256, 0, stream>>>(ctr, keys, bcount);
  k_sel<<<1, 1024, 0, stream>>>(keys, bcount,
                                cand_val, cand_bid, cand_cy, cand_cx, barcnt);
  k_mega<<<GRID, 256, 0, stream>>>(offs, sem, mix,
                                   cand_val, cand_bid, cand_cy, cand_cx, selected,
                                   gsy, gsx, gcn, barcnt, out);
}

// Round 14
// 51.894 us; speedup vs baseline: 3.5006x; 3.5006x over previous
//
#include <hip/hip_runtime.h>

// ---------------- problem constants ----------------
constexpr int B_ = 2, H_ = 512, W_ = 512;
constexpr int HWl = H_ * W_;          // 262144
constexpr int TOT = B_ * HWl;         // 524288
constexpr int KC = 200;               // TOP_K_INSTANCE
constexpr int NBLK = 256;             // k_nms blocks (128 row-tiles x 2 batches)
constexpr int BINOFF = 0x3DCCC;       // (bits(0.1f))>>12 : floor of thresholded values
constexpr float INV2S2 = 0.0078125f;  // 1/128, exact power of 2

// output layout (flat float32, concatenated in return order)
constexpr int OUT_CENTER = 0;                 // [B,1,H,W]
constexpr int OUT_OFF = TOT;                  // [B,2,H,W]
constexpr int OUT_CW = 3 * TOT;               // [B,H,W] ones
constexpr int OUT_OW = 4 * TOT;               // [B,H,W] fg

__device__ __forceinline__ float hwthr(float v) { return v > 0.1f ? v : -1.0f; }
__device__ __forceinline__ float4 max4(float4 a, float4 b) {
  return make_float4(fmaxf(a.x, b.x), fmaxf(a.y, b.y), fmaxf(a.z, b.z), fmaxf(a.w, b.w));
}
// monotone fine bin on value bits [31:12]; ~260 peaks max per bin
__device__ __forceinline__ int finebin(unsigned long long kk) {
  int bq = (int)(kk >> 44) - BINOFF;            // key32>>12 - offset
  return bq < 0 ? 0 : (bq > 8191 ? 8191 : bq);
}

// ---------------- kernels ----------------

// fused threshold + separable 7x7 NMS, LDS-tiled (4 output rows + 3-row halo).
// 512 threads/block (8 waves/CU) to hide halo-load latency; no global atomics.
__global__ __launch_bounds__(512) void k_nms(const float* __restrict__ ctr,
                                             unsigned long long* __restrict__ keys,
                                             int* __restrict__ bcount) {
  __shared__ float rmx[10 * 512];
  __shared__ unsigned long long lkeys[1024];
  __shared__ int lnum;
  int tid = threadIdx.x, blk = blockIdx.x;     // NBLK blocks
  int b = blk >> 7, y0 = (blk & 127) << 2;     // output rows y0..y0+3
  if (tid == 0) lnum = 0;
  const float4* c4p = (const float4*)(ctr + b * HWl);
  // horizontal 7-max of thresholded heatmap for rows y0-3 .. y0+6
  for (int u = tid; u < 1280; u += 512) {
    int r = u >> 7, c4 = u & 127, gy = y0 - 3 + r;
    float4 m = make_float4(-1e30f, -1e30f, -1e30f, -1e30f);
    if (gy >= 0 && gy < H_) {
      float4 v = c4p[gy * 128 + c4];
      float4 L = make_float4(-1e30f, -1e30f, -1e30f, -1e30f), R = L;
      if (c4 > 0) L = c4p[gy * 128 + c4 - 1];
      if (c4 < 127) R = c4p[gy * 128 + c4 + 1];
      float a1 = hwthr(L.y), a2 = hwthr(L.z), a3 = hwthr(L.w);
      float a4 = hwthr(v.x), a5 = hwthr(v.y), a6 = hwthr(v.z), a7 = hwthr(v.w);
      float a8 = hwthr(R.x), a9 = hwthr(R.y), a10 = hwthr(R.z);
      float core = fmaxf(fmaxf(a4, a5), fmaxf(a6, a7));
      m.x = fmaxf(fmaxf(a1, a2), fmaxf(a3, core));
      m.y = fmaxf(fmaxf(a2, a3), fmaxf(core, a8));
      m.z = fmaxf(fmaxf(a3, core), fmaxf(a8, a9));
      m.w = fmaxf(fmaxf(core, a8), fmaxf(a9, a10));
    }
    ((float4*)rmx)[u] = m;
  }
  __syncthreads();
  // vertical 7-max + peak emit (one float4 column-slot per thread)
  if (tid < 512) {
    int u = tid;
    int orr = u >> 7, c4 = u & 127;
    int y = y0 + orr;
    float4 pool = ((float4*)rmx)[orr * 128 + c4];
#pragma unroll
    for (int r = 1; r <= 6; ++r)
      pool = max4(pool, ((float4*)rmx)[(orr + r) * 128 + c4]);
    float4 v = c4p[y * 128 + c4];
    float vv[4] = {v.x, v.y, v.z, v.w};
    float pv[4] = {pool.x, pool.y, pool.z, pool.w};
#pragma unroll
    for (int j = 0; j < 4; ++j) {
      float vj = vv[j];
      if (vj > 0.1f && vj == pv[j]) {  // exact equality, same as reference hmp==pooled
        unsigned int i = (unsigned int)(b * HWl + y * W_ + c4 * 4 + j);
        unsigned long long comp = ((unsigned long long)__float_as_uint(vj) << 32)
                                | (unsigned long long)(0xFFFFFFFFu - i);
        int slot = atomicAdd(&lnum, 1);  // LDS atomic, cheap
        if (slot < 1024) lkeys[slot] = comp;
      }
    }
  }
  __syncthreads();
  int n = lnum; if (n > 1024) n = 1024;
  if (tid == 0) bcount[blk] = n;
  for (int q = tid; q < n; q += 512) keys[blk * 1024 + q] = lkeys[q];
}

// single selection kernel: build the 8192-bin fine histogram IN LDS from the
// L2-hot keys (4 threads/segment), suffix-scan -> P1, second filtered pass
// (survivors <= ~460 < 1024), exact rank by 64-bit comparison (unique keys ->
// (value desc, index asc) order).
__global__ __launch_bounds__(1024) void k_sel(
    const unsigned long long* __restrict__ keys, const int* __restrict__ bcount,
    float* __restrict__ cand_val, int* __restrict__ cand_bid,
    int* __restrict__ cand_cy, int* __restrict__ cand_cx) {
  __shared__ int hist[8192];          // 32 KB
  __shared__ int sfx[1024];
  __shared__ int bc[NBLK];
  __shared__ int s_P1, ln;
  __shared__ unsigned long long wk[1024];
  int tid = threadIdx.x;
  if (tid == 0) { s_P1 = 0; ln = 0; }
  if (tid < NBLK) { int c = bcount[tid]; bc[tid] = c > 1024 ? 1024 : c; }
  for (int q = tid; q < 8192; q += 1024) hist[q] = 0;
  __syncthreads();
  // ---- build LDS hist: 4 threads/segment, ~11 L2-hot loads each ----
  int seg = tid >> 2, sub = tid & 3;
  int nn = bc[seg];
  for (int q = sub; q < nn; q += 4)
    atomicAdd(&hist[finebin(keys[seg * 1024 + q])], 1);
  __syncthreads();
  // ---- suffix scan (8 bins/thread) -> P1 ----
  int bins[8];
  int cs = 0;
#pragma unroll
  for (int q = 0; q < 8; ++q) { bins[q] = hist[tid * 8 + q]; cs += bins[q]; }
  sfx[tid] = cs;
  __syncthreads();
  for (int off = 1; off < 1024; off <<= 1) {
    int v = (tid + off < 1024) ? sfx[tid + off] : 0;
    __syncthreads();
    sfx[tid] += v;
    __syncthreads();
  }
  int total = sfx[0];
  if (total > KC) {
    int above = (tid == 1023) ? 0 : sfx[tid + 1];
    if (sfx[tid] >= KC && above < KC) {
      int acc = above;
#pragma unroll
      for (int bq = 7; bq >= 0; --bq) {
        acc += bins[bq];
        if (acc >= KC) { s_P1 = tid * 8 + bq; break; }
      }
    }
  }
  __syncthreads();
  int P1 = s_P1;
  // ---- filter all segments (second L2-hot pass) ----
  for (int q = sub; q < nn; q += 4) {
    unsigned long long kk = keys[seg * 1024 + q];
    if (finebin(kk) >= P1) {
      int w2 = atomicAdd(&ln, 1);
      if (w2 < 1024) wk[w2] = kk;
    }
  }
  __syncthreads();
  int n = ln > 1024 ? 1024 : ln;
  // ---- exact rank by comparison (keys unique -> unique ranks) ----
  if (tid < n) {
    unsigned long long mine = wk[tid];
    int r = 0;
    for (int j = 0; j < n; ++j) r += (wk[j] > mine) ? 1 : 0;
    if (r < KC) {
      unsigned int key32 = (unsigned int)(mine >> 32);
      unsigned int idx = 0xFFFFFFFFu - (unsigned int)(mine & 0xFFFFFFFFULL);
      int bb = (int)(idx >> 18), rem = (int)(idx & (HWl - 1));
      cand_val[r] = __uint_as_float(key32);
      cand_bid[r] = bb; cand_cy[r] = rem >> 9; cand_cx[r] = rem & (W_ - 1);
    }
  }
  if (tid >= n && tid < KC) {  // unfilled slots (only when n < KC)
    cand_val[tid] = -1e30f; cand_bid[tid] = 0; cand_cy[tid] = 0; cand_cx[tid] = 0;
  }
}

// per-candidate window count of thing pixels (exact integer == f32 integral
// image). One wave per window row (window <= 51 wide <= 64 lanes: no div/mod).
// Block 0 also zeroes the global segment sums (written only by later k_fused).
__global__ __launch_bounds__(256) void k_wsum(
    const int* __restrict__ sem, const float* __restrict__ mix,
    const float* __restrict__ cand_val, const int* __restrict__ cand_bid,
    const int* __restrict__ cand_cy, const int* __restrict__ cand_cx,
    int* __restrict__ selected, int* __restrict__ gz) {
  __shared__ int ssum[256];
  if (blockIdx.x == 0) {
    for (int q = threadIdx.x; q < 3 * (KC + 1) * B_; q += 256) gz[q] = 0;
  }
  int k = blockIdx.x;
  int b = cand_bid[k], cy = cand_cy[k], cx = cand_cx[k];
  float v = cand_val[k];
  int y0 = cy - 25; if (y0 < 0) y0 = 0;
  int y1 = cy + 26; if (y1 > H_) y1 = H_;
  int x0 = cx - 25; if (x0 < 0) x0 = 0;
  int x1 = cx + 26; if (x1 > W_) x1 = W_;
  int wd = x1 - x0, nr = y1 - y0;               // both <= 51
  int wave = threadIdx.x >> 6, lane = threadIdx.x & 63;
  int s = 0;
  for (int rr = wave; rr < nr; rr += 4) {
    if (lane < wd) {
      int sv = sem[b * HWl + (y0 + rr) * W_ + x0 + lane];
      s += (sv >= 11 && sv <= 18) ? 1 : 0;
    }
  }
  ssum[threadIdx.x] = s;
  __syncthreads();
  for (int o = 128; o > 0; o >>= 1) {
    if (threadIdx.x < o) ssum[threadIdx.x] += ssum[threadIdx.x + o];
    __syncthreads();
  }
  if (threadIdx.x == 0) {
    bool sel = (v >= 0.1f) && (mix[b * HWl + cy * W_ + cx] < 0.5f) && (ssum[0] >= 64);
    selected[k] = sel ? 1 : 0;
  }
}

// fused (4 px/thread): inline center-list build (per-block ballot compaction),
// nearest-center argmin, Gaussian max-splat over a prefiltered local list,
// instance ids + local 201-bin LDS mass sums flushed to global per block
__global__ __launch_bounds__(256) void k_fused(
    const float* __restrict__ offs, const int* __restrict__ sem,
    const int* __restrict__ cand_bid, const int* __restrict__ cand_cy,
    const int* __restrict__ cand_cx, const int* __restrict__ selected,
    int* __restrict__ ins, float* __restrict__ out,
    int* __restrict__ gsy, int* __restrict__ gsx, int* __restrict__ gcn) {
  __shared__ float4 sc[KC];
  __shared__ float2 gl[KC];
  __shared__ int lsy[KC + 1], lsx[KC + 1], lcn[KC + 1];
  __shared__ int wtot[4];
  __shared__ int gcnt_s;
  int tid = threadIdx.x;
  int t = blockIdx.x * 256 + tid;   // t < 131072
  int p = t << 2;
  int b = p >> 18;                  // uniform per block
  int rem = p & (HWl - 1), y = rem >> 9, x0i = rem & (W_ - 1);
  int yA = (int)(((unsigned)(blockIdx.x * 1024) & (HWl - 1)) >> 9);  // block's first row

  for (int q = tid; q <= KC; q += 256) { lsy[q] = 0; lsx[q] = 0; lcn[q] = 0; }
  if (tid == 0) gcnt_s = 0;
  // ---- build this batch's packed center list (rank order preserved) ----
  bool sel = false; int cb = 0, ccy = 0, ccx = 0;
  if (tid < KC) { sel = selected[tid] != 0; cb = cand_bid[tid]; ccy = cand_cy[tid]; ccx = cand_cx[tid]; }
  bool mine = sel && (cb == b);
  unsigned long long mk = __ballot(mine);
  int lane = tid & 63, wv = tid >> 6;
  if (lane == 0) wtot[wv] = __popcll(mk);
  __syncthreads();
  int base = 0;
  for (int w2 = 0; w2 < wv; ++w2) base += wtot[w2];
  int S = wtot[0] + wtot[1] + wtot[2] + wtot[3];
  if (mine) {
    int pos = base + __popcll(mk & ((1ULL << lane) - 1ULL));
    float fyc = (float)ccy, fxc = (float)ccx;
    float cc = __fadd_rn(__fmul_rn(fyc, fyc), __fmul_rn(fxc, fxc));
    sc[pos] = make_float4(fyc, fxc, cc, 0.0f);
  }
  __syncthreads();
  // ---- prefilter Gaussian-relevant centers for this block's rows ----
  if (tid < S) {
    float cyv = sc[tid].x;
    if (cyv >= (float)(yA - 25) && cyv <= (float)(yA + 26)) {
      int gp = atomicAdd(&gcnt_s, 1);
      gl[gp] = make_float2(cyv, sc[tid].y);
    }
  }
  __syncthreads();
  int G = gcnt_s;

  float fy = (float)y;
  float4 oy4 = *(const float4*)(offs + b * 2 * HWl + rem);
  float4 ox4 = *(const float4*)(offs + b * 2 * HWl + HWl + rem);
  float oyv[4] = {oy4.x, oy4.y, oy4.z, oy4.w};
  float oxv[4] = {ox4.x, ox4.y, ox4.z, ox4.w};
  float lyv[4], lxv[4], llv[4], bd[4];
  int bsg[4];
#pragma unroll
  for (int j = 0; j < 4; ++j) {
    float fx = (float)(x0i + j);
    // exact op order of reference: ll = ly*ly + lx*lx (no FMA)
    lyv[j] = __fadd_rn(fy, oyv[j]);
    lxv[j] = __fadd_rn(fx, oxv[j]);
    llv[j] = __fadd_rn(__fmul_rn(lyv[j], lyv[j]), __fmul_rn(lxv[j], lxv[j]));
    bd[j] = 3.0e38f; bsg[j] = 0;
  }
  // argmin over all S (exact expanded-quadratic op order; first-min tie-break)
  for (int s = 0; s < S; ++s) {
    float4 c = sc[s];
#pragma unroll
    for (int j = 0; j < 4; ++j) {
      float dot = __fadd_rn(__fmul_rn(c.x, lyv[j]), __fmul_rn(c.y, lxv[j]));
      float d2 = __fadd_rn(__fsub_rn(c.z, __fmul_rn(2.0f, dot)), llv[j]);
      bool better = d2 < bd[j];
      bd[j] = better ? d2 : bd[j];
      bsg[j] = better ? (s + 1) : bsg[j];
    }
  }
  // Gaussian max-splat over prefiltered list (fp max is order-independent)
  float bg[4] = {0.0f, 0.0f, 0.0f, 0.0f};
  for (int g = 0; g < G; ++g) {
    float2 gc = gl[g];
    float dyc = fy - gc.x;
    if (fabsf(dyc) <= 25.0f) {
      float gy = expf(-__fmul_rn(__fmul_rn(dyc, dyc), INV2S2));
#pragma unroll
      for (int j = 0; j < 4; ++j) {
        float dxc = (float)(x0i + j) - gc.y;
        if (fabsf(dxc) <= 25.0f) {
          float gx = expf(-__fmul_rn(__fmul_rn(dxc, dxc), INV2S2));
          bg[j] = fmaxf(bg[j], __fmul_rn(gy, gx));
        }
      }
    }
  }
  *(float4*)(out + OUT_CENTER + p) = make_float4(bg[0], bg[1], bg[2], bg[3]);
  int4 sv4 = *(const int4*)(sem + p);
  int svv[4] = {sv4.x, sv4.y, sv4.z, sv4.w};
  int insv[4];
  bool s_any = S > 0;
#pragma unroll
  for (int j = 0; j < 4; ++j) {
    bool thing = (svv[j] >= 11 && svv[j] <= 18);
    insv[j] = (thing && s_any) ? bsg[j] : 0;
  }
  *(int4*)(ins + p) = make_int4(insv[0], insv[1], insv[2], insv[3]);
  // merged per-thread local-bin accumulation (adjacent px often share a segment)
  int curSeg = -1, aY = 0, aX = 0, aC = 0;
#pragma unroll
  for (int j = 0; j < 4; ++j) {
    if (insv[j] > 0) {
      int sg = insv[j];
      if (sg != curSeg) {
        if (curSeg >= 0) {
          atomicAdd(&lsy[curSeg], aY); atomicAdd(&lsx[curSeg], aX); atomicAdd(&lcn[curSeg], aC);
        }
        curSeg = sg; aY = 0; aX = 0; aC = 0;
      }
      aY += y; aX += x0i + j; aC += 1;
    }
  }
  if (curSeg >= 0) {
    atomicAdd(&lsy[curSeg], aY); atomicAdd(&lsx[curSeg], aX); atomicAdd(&lcn[curSeg], aC);
  }
  __syncthreads();
  for (int q = tid; q <= KC; q += 256) {
    int c = lcn[q];
    if (c) {
      int gq = b * (KC + 1) + q;
      atomicAdd(&gcn[gq], c); atomicAdd(&gsy[gq], lsy[q]); atomicAdd(&gsx[gq], lsx[q]);
    }
  }
}

// offsets (4 px/thread) + center/offset weights
__global__ __launch_bounds__(256) void k_off(
    const int* __restrict__ ins, const int* __restrict__ gsy,
    const int* __restrict__ gsx, const int* __restrict__ gcn,
    float* __restrict__ out) {
  int t = blockIdx.x * 256 + threadIdx.x;   // t < 131072
  int p = t << 2;
  int b = p >> 18, rem = p & (HWl - 1), y = rem >> 9, x0i = rem & (W_ - 1);
  int4 iv = *(const int4*)(ins + p);
  int insv[4] = {iv.x, iv.y, iv.z, iv.w};
  float oy[4], ox[4], ow[4];
  float fy = (float)y;
#pragma unroll
  for (int j = 0; j < 4; ++j) {
    if (insv[j] > 0) {
      int sg = b * (KC + 1) + insv[j];
      float c = fmaxf((float)gcn[sg], 1.0f);
      oy[j] = __fsub_rn((float)gsy[sg] / c, fy);
      ox[j] = __fsub_rn((float)gsx[sg] / c, (float)(x0i + j));
      ow[j] = 1.0f;
    } else { oy[j] = 0.0f; ox[j] = 0.0f; ow[j] = 0.0f; }
  }
  *(float4*)(out + OUT_OFF + b * 2 * HWl + rem) = make_float4(oy[0], oy[1], oy[2], oy[3]);
  *(float4*)(out + OUT_OFF + b * 2 * HWl + HWl + rem) = make_float4(ox[0], ox[1], ox[2], ox[3]);
  *(float4*)(out + OUT_CW + p) = make_float4(1.0f, 1.0f, 1.0f, 1.0f);
  *(float4*)(out + OUT_OW + p) = make_float4(ow[0], ow[1], ow[2], ow[3]);
}

// ---------------- launch ----------------
extern "C" void kernel_launch(void* const* d_in, const int* in_sizes, int n_in,
                              void* d_out, int out_size, void* d_ws, size_t ws_size,
                              hipStream_t stream) {
  const float* ctr = (const float*)d_in[0];
  const float* offs = (const float*)d_in[1];
  const int* sem = (const int*)d_in[2];
  const float* mix = (const float*)d_in[3];
  float* out = (float*)d_out;

  char* w = (char*)d_ws;
  int* gz = (int*)(w + 0);                              // gsy|gsx|gcn, 3*402 ints
  int* gsy = gz;                                        // [zeroed by k_wsum blk 0]
  int* gsx = gz + (KC + 1) * B_;
  int* gcn = gz + 2 * (KC + 1) * B_;                    // ends 4824
  int* bcount = (int*)(w + 8192);                       // 256 ints, fully rewritten
  float* cand_val = (float*)(w + 10240);
  int* cand_bid = (int*)(w + 11264);
  int* cand_cy = (int*)(w + 12288);
  int* cand_cx = (int*)(w + 13312);
  int* selected = (int*)(w + 14336);
  // keys: NBLK*1024*8 = 2 MB; ins (2 MB) OVERLAYS keys (keys dead after
  // k_sel; k_fused runs strictly later in-stream).
  unsigned long long* keys = (unsigned long long*)(w + 65536);
  int* ins = (int*)(w + 65536);

  k_nms<<<NBLK, 512, 0, stream>>>(ctr, keys, bcount);
  k_sel<<<1, 1024, 0, stream>>>(keys, bcount,
                                cand_val, cand_bid, cand_cy, cand_cx);
  k_wsum<<<KC, 256, 0, stream>>>(sem, mix, cand_val, cand_bid, cand_cy, cand_cx,
                                 selected, gz);
  k_fused<<<512, 256, 0, stream>>>(offs, sem, cand_bid, cand_cy, cand_cx, selected,
                                   ins, out, gsy, gsx, gcn);
  k_off<<<512, 256, 0, stream>>>(ins, gsy, gsx, gcn, out);
}

// Round 15
// 48.882 us; speedup vs baseline: 3.7162x; 1.0616x over previous
//
#include <hip/hip_runtime.h>

// ---------------- problem constants ----------------
constexpr int B_ = 2, H_ = 512, W_ = 512;
constexpr int HWl = H_ * W_;          // 262144
constexpr int TOT = B_ * HWl;         // 524288
constexpr int KC = 200;               // TOP_K_INSTANCE
constexpr int NBLK = 256;             // k_nms blocks (128 row-tiles x 2 batches)
constexpr int BINOFF = 0x3DCCC;       // (bits(0.1f))>>12 : floor of thresholded values
constexpr int KREG = 24;              // per-thread register key cache (96/segment, ~8 sigma)
constexpr float INV2S2 = 0.0078125f;  // 1/128, exact power of 2

// output layout (flat float32, concatenated in return order)
constexpr int OUT_CENTER = 0;                 // [B,1,H,W]
constexpr int OUT_OFF = TOT;                  // [B,2,H,W]
constexpr int OUT_CW = 3 * TOT;               // [B,H,W] ones
constexpr int OUT_OW = 4 * TOT;               // [B,H,W] fg

__device__ __forceinline__ float hwthr(float v) { return v > 0.1f ? v : -1.0f; }
__device__ __forceinline__ float4 max4(float4 a, float4 b) {
  return make_float4(fmaxf(a.x, b.x), fmaxf(a.y, b.y), fmaxf(a.z, b.z), fmaxf(a.w, b.w));
}
// monotone fine bin on value bits [31:12]; ~260 peaks max per bin
__device__ __forceinline__ int finebin(unsigned long long kk) {
  int bq = (int)(kk >> 44) - BINOFF;            // key32>>12 - offset
  return bq < 0 ? 0 : (bq > 8191 ? 8191 : bq);
}

// ---------------- kernels ----------------

// fused threshold + separable 7x7 NMS, LDS-tiled (4 output rows + 3-row halo).
// Peaks staged in LDS -> per-block key segment (plain bcount store).
__global__ __launch_bounds__(256) void k_nms(const float* __restrict__ ctr,
                                             unsigned long long* __restrict__ keys,
                                             int* __restrict__ bcount) {
  __shared__ float rmx[10 * 512];
  __shared__ unsigned long long lkeys[1024];
  __shared__ int lnum;
  int tid = threadIdx.x, blk = blockIdx.x;     // NBLK blocks
  int b = blk >> 7, y0 = (blk & 127) << 2;     // output rows y0..y0+3
  if (tid == 0) lnum = 0;
  const float4* c4p = (const float4*)(ctr + b * HWl);
  // horizontal 7-max of thresholded heatmap for rows y0-3 .. y0+6
  for (int u = tid; u < 1280; u += 256) {
    int r = u >> 7, c4 = u & 127, gy = y0 - 3 + r;
    float4 m = make_float4(-1e30f, -1e30f, -1e30f, -1e30f);
    if (gy >= 0 && gy < H_) {
      float4 v = c4p[gy * 128 + c4];
      float4 L = make_float4(-1e30f, -1e30f, -1e30f, -1e30f), R = L;
      if (c4 > 0) L = c4p[gy * 128 + c4 - 1];
      if (c4 < 127) R = c4p[gy * 128 + c4 + 1];
      float a1 = hwthr(L.y), a2 = hwthr(L.z), a3 = hwthr(L.w);
      float a4 = hwthr(v.x), a5 = hwthr(v.y), a6 = hwthr(v.z), a7 = hwthr(v.w);
      float a8 = hwthr(R.x), a9 = hwthr(R.y), a10 = hwthr(R.z);
      float core = fmaxf(fmaxf(a4, a5), fmaxf(a6, a7));
      m.x = fmaxf(fmaxf(a1, a2), fmaxf(a3, core));
      m.y = fmaxf(fmaxf(a2, a3), fmaxf(core, a8));
      m.z = fmaxf(fmaxf(a3, core), fmaxf(a8, a9));
      m.w = fmaxf(fmaxf(core, a8), fmaxf(a9, a10));
    }
    ((float4*)rmx)[u] = m;
  }
  __syncthreads();
  // vertical 7-max + peak emit
  for (int u = tid; u < 512; u += 256) {
    int orr = u >> 7, c4 = u & 127;
    int y = y0 + orr;
    float4 pool = ((float4*)rmx)[orr * 128 + c4];
#pragma unroll
    for (int r = 1; r <= 6; ++r)
      pool = max4(pool, ((float4*)rmx)[(orr + r) * 128 + c4]);
    float4 v = c4p[y * 128 + c4];
    float vv[4] = {v.x, v.y, v.z, v.w};
    float pv[4] = {pool.x, pool.y, pool.z, pool.w};
#pragma unroll
    for (int j = 0; j < 4; ++j) {
      float vj = vv[j];
      if (vj > 0.1f && vj == pv[j]) {  // exact equality, same as reference hmp==pooled
        unsigned int i = (unsigned int)(b * HWl + y * W_ + c4 * 4 + j);
        unsigned long long comp = ((unsigned long long)__float_as_uint(vj) << 32)
                                | (unsigned long long)(0xFFFFFFFFu - i);
        int slot = atomicAdd(&lnum, 1);  // LDS atomic, cheap
        if (slot < 1024) lkeys[slot] = comp;
      }
    }
  }
  __syncthreads();
  int n = lnum; if (n > 1024) n = 1024;
  if (tid == 0) bcount[blk] = n;
  for (int q = tid; q < n; q += 256) keys[blk * 1024 + q] = lkeys[q];
}

// single selection kernel: ONE global pass (keys cached in registers, 24
// unrolled independent loads -> high MLP) builds the 8192-bin LDS histogram;
// suffix-scan -> P1; filter from REGISTERS (global fallback only for >96-key
// segments, never in practice); exact rank by 64-bit comparison.
__global__ __launch_bounds__(1024) void k_sel(
    const unsigned long long* __restrict__ keys, const int* __restrict__ bcount,
    float* __restrict__ cand_val, int* __restrict__ cand_bid,
    int* __restrict__ cand_cy, int* __restrict__ cand_cx) {
  __shared__ int hist[8192];          // 32 KB
  __shared__ int sfx[1024];
  __shared__ int bc[NBLK];
  __shared__ int s_P1, ln;
  __shared__ unsigned long long wk[1024];
  int tid = threadIdx.x;
  if (tid == 0) { s_P1 = 0; ln = 0; }
  if (tid < NBLK) { int c = bcount[tid]; bc[tid] = c > 1024 ? 1024 : c; }
  for (int q = tid; q < 8192; q += 1024) hist[q] = 0;
  __syncthreads();
  // ---- single global pass: load into regs (static indices) + LDS hist ----
  int seg = tid >> 2, sub = tid & 3;
  int nn = bc[seg];
  unsigned long long kreg[KREG];
#pragma unroll
  for (int i = 0; i < KREG; ++i) {
    int q = sub + 4 * i;
    unsigned long long kk = 0ULL;     // 0 = impossible key (value >= 0.1 bits)
    if (q < nn) kk = keys[seg * 1024 + q];
    kreg[i] = kk;
    if (kk) atomicAdd(&hist[finebin(kk)], 1);
  }
  for (int q = sub + 4 * KREG; q < nn; q += 4) {   // never fires at ~42/segment
    unsigned long long kk = keys[seg * 1024 + q];
    atomicAdd(&hist[finebin(kk)], 1);
  }
  __syncthreads();
  // ---- suffix scan (8 bins/thread) -> P1 ----
  int bins[8];
  int cs = 0;
#pragma unroll
  for (int q = 0; q < 8; ++q) { bins[q] = hist[tid * 8 + q]; cs += bins[q]; }
  sfx[tid] = cs;
  __syncthreads();
  for (int off = 1; off < 1024; off <<= 1) {
    int v = (tid + off < 1024) ? sfx[tid + off] : 0;
    __syncthreads();
    sfx[tid] += v;
    __syncthreads();
  }
  int total = sfx[0];
  if (total > KC) {
    int above = (tid == 1023) ? 0 : sfx[tid + 1];
    if (sfx[tid] >= KC && above < KC) {
      int acc = above;
#pragma unroll
      for (int bq = 7; bq >= 0; --bq) {
        acc += bins[bq];
        if (acc >= KC) { s_P1 = tid * 8 + bq; break; }
      }
    }
  }
  __syncthreads();
  int P1 = s_P1;
  // ---- filter from registers (no second global pass) ----
#pragma unroll
  for (int i = 0; i < KREG; ++i) {
    unsigned long long kk = kreg[i];
    if (kk && finebin(kk) >= P1) {
      int w2 = atomicAdd(&ln, 1);
      if (w2 < 1024) wk[w2] = kk;
    }
  }
  for (int q = sub + 4 * KREG; q < nn; q += 4) {   // never fires in practice
    unsigned long long kk = keys[seg * 1024 + q];
    if (finebin(kk) >= P1) {
      int w2 = atomicAdd(&ln, 1);
      if (w2 < 1024) wk[w2] = kk;
    }
  }
  __syncthreads();
  int n = ln > 1024 ? 1024 : ln;
  // ---- exact rank by comparison (keys unique -> unique ranks) ----
  if (tid < n) {
    unsigned long long mine = wk[tid];
    int r = 0;
    for (int j = 0; j < n; ++j) r += (wk[j] > mine) ? 1 : 0;
    if (r < KC) {
      unsigned int key32 = (unsigned int)(mine >> 32);
      unsigned int idx = 0xFFFFFFFFu - (unsigned int)(mine & 0xFFFFFFFFULL);
      int bb = (int)(idx >> 18), rem = (int)(idx & (HWl - 1));
      cand_val[r] = __uint_as_float(key32);
      cand_bid[r] = bb; cand_cy[r] = rem >> 9; cand_cx[r] = rem & (W_ - 1);
    }
  }
  if (tid >= n && tid < KC) {  // unfilled slots (only when n < KC)
    cand_val[tid] = -1e30f; cand_bid[tid] = 0; cand_cy[tid] = 0; cand_cx[tid] = 0;
  }
}

// per-candidate window count of thing pixels (exact integer == f32 integral
// image). One wave per window row (window <= 51 wide <= 64 lanes: no div/mod).
// Block 0 also zeroes the global segment sums (written only by later k_fused).
__global__ __launch_bounds__(256) void k_wsum(
    const int* __restrict__ sem, const float* __restrict__ mix,
    const float* __restrict__ cand_val, const int* __restrict__ cand_bid,
    const int* __restrict__ cand_cy, const int* __restrict__ cand_cx,
    int* __restrict__ selected, int* __restrict__ gz) {
  __shared__ int ssum[256];
  if (blockIdx.x == 0) {
    for (int q = threadIdx.x; q < 3 * (KC + 1) * B_; q += 256) gz[q] = 0;
  }
  int k = blockIdx.x;
  int b = cand_bid[k], cy = cand_cy[k], cx = cand_cx[k];
  float v = cand_val[k];
  int y0 = cy - 25; if (y0 < 0) y0 = 0;
  int y1 = cy + 26; if (y1 > H_) y1 = H_;
  int x0 = cx - 25; if (x0 < 0) x0 = 0;
  int x1 = cx + 26; if (x1 > W_) x1 = W_;
  int wd = x1 - x0, nr = y1 - y0;               // both <= 51
  int wave = threadIdx.x >> 6, lane = threadIdx.x & 63;
  int s = 0;
  for (int rr = wave; rr < nr; rr += 4) {
    if (lane < wd) {
      int sv = sem[b * HWl + (y0 + rr) * W_ + x0 + lane];
      s += (sv >= 11 && sv <= 18) ? 1 : 0;
    }
  }
  ssum[threadIdx.x] = s;
  __syncthreads();
  for (int o = 128; o > 0; o >>= 1) {
    if (threadIdx.x < o) ssum[threadIdx.x] += ssum[threadIdx.x + o];
    __syncthreads();
  }
  if (threadIdx.x == 0) {
    bool sel = (v >= 0.1f) && (mix[b * HWl + cy * W_ + cx] < 0.5f) && (ssum[0] >= 64);
    selected[k] = sel ? 1 : 0;
  }
}

// fused (4 px/thread): inline center-list build (per-block ballot compaction),
// nearest-center argmin, Gaussian max-splat over a prefiltered local list,
// instance ids + local 201-bin LDS mass sums flushed to global per block
__global__ __launch_bounds__(256) void k_fused(
    const float* __restrict__ offs, const int* __restrict__ sem,
    const int* __restrict__ cand_bid, const int* __restrict__ cand_cy,
    const int* __restrict__ cand_cx, const int* __restrict__ selected,
    int* __restrict__ ins, float* __restrict__ out,
    int* __restrict__ gsy, int* __restrict__ gsx, int* __restrict__ gcn) {
  __shared__ float4 sc[KC];
  __shared__ float2 gl[KC];
  __shared__ int lsy[KC + 1], lsx[KC + 1], lcn[KC + 1];
  __shared__ int wtot[4];
  __shared__ int gcnt_s;
  int tid = threadIdx.x;
  int t = blockIdx.x * 256 + tid;   // t < 131072
  int p = t << 2;
  int b = p >> 18;                  // uniform per block
  int rem = p & (HWl - 1), y = rem >> 9, x0i = rem & (W_ - 1);
  int yA = (int)(((unsigned)(blockIdx.x * 1024) & (HWl - 1)) >> 9);  // block's first row

  for (int q = tid; q <= KC; q += 256) { lsy[q] = 0; lsx[q] = 0; lcn[q] = 0; }
  if (tid == 0) gcnt_s = 0;
  // ---- build this batch's packed center list (rank order preserved) ----
  bool sel = false; int cb = 0, ccy = 0, ccx = 0;
  if (tid < KC) { sel = selected[tid] != 0; cb = cand_bid[tid]; ccy = cand_cy[tid]; ccx = cand_cx[tid]; }
  bool mine = sel && (cb == b);
  unsigned long long mk = __ballot(mine);
  int lane = tid & 63, wv = tid >> 6;
  if (lane == 0) wtot[wv] = __popcll(mk);
  __syncthreads();
  int base = 0;
  for (int w2 = 0; w2 < wv; ++w2) base += wtot[w2];
  int S = wtot[0] + wtot[1] + wtot[2] + wtot[3];
  if (mine) {
    int pos = base + __popcll(mk & ((1ULL << lane) - 1ULL));
    float fyc = (float)ccy, fxc = (float)ccx;
    float cc = __fadd_rn(__fmul_rn(fyc, fyc), __fmul_rn(fxc, fxc));
    sc[pos] = make_float4(fyc, fxc, cc, 0.0f);
  }
  __syncthreads();
  // ---- prefilter Gaussian-relevant centers for this block's rows ----
  if (tid < S) {
    float cyv = sc[tid].x;
    if (cyv >= (float)(yA - 25) && cyv <= (float)(yA + 26)) {
      int gp = atomicAdd(&gcnt_s, 1);
      gl[gp] = make_float2(cyv, sc[tid].y);
    }
  }
  __syncthreads();
  int G = gcnt_s;

  float fy = (float)y;
  float4 oy4 = *(const float4*)(offs + b * 2 * HWl + rem);
  float4 ox4 = *(const float4*)(offs + b * 2 * HWl + HWl + rem);
  float oyv[4] = {oy4.x, oy4.y, oy4.z, oy4.w};
  float oxv[4] = {ox4.x, ox4.y, ox4.z, ox4.w};
  float lyv[4], lxv[4], llv[4], bd[4];
  int bsg[4];
#pragma unroll
  for (int j = 0; j < 4; ++j) {
    float fx = (float)(x0i + j);
    // exact op order of reference: ll = ly*ly + lx*lx (no FMA)
    lyv[j] = __fadd_rn(fy, oyv[j]);
    lxv[j] = __fadd_rn(fx, oxv[j]);
    llv[j] = __fadd_rn(__fmul_rn(lyv[j], lyv[j]), __fmul_rn(lxv[j], lxv[j]));
    bd[j] = 3.0e38f; bsg[j] = 0;
  }
  // argmin over all S (exact expanded-quadratic op order; first-min tie-break)
  for (int s = 0; s < S; ++s) {
    float4 c = sc[s];
#pragma unroll
    for (int j = 0; j < 4; ++j) {
      float dot = __fadd_rn(__fmul_rn(c.x, lyv[j]), __fmul_rn(c.y, lxv[j]));
      float d2 = __fadd_rn(__fsub_rn(c.z, __fmul_rn(2.0f, dot)), llv[j]);
      bool better = d2 < bd[j];
      bd[j] = better ? d2 : bd[j];
      bsg[j] = better ? (s + 1) : bsg[j];
    }
  }
  // Gaussian max-splat over prefiltered list (fp max is order-independent)
  float bg[4] = {0.0f, 0.0f, 0.0f, 0.0f};
  for (int g = 0; g < G; ++g) {
    float2 gc = gl[g];
    float dyc = fy - gc.x;
    if (fabsf(dyc) <= 25.0f) {
      float gy = expf(-__fmul_rn(__fmul_rn(dyc, dyc), INV2S2));
#pragma unroll
      for (int j = 0; j < 4; ++j) {
        float dxc = (float)(x0i + j) - gc.y;
        if (fabsf(dxc) <= 25.0f) {
          float gx = expf(-__fmul_rn(__fmul_rn(dxc, dxc), INV2S2));
          bg[j] = fmaxf(bg[j], __fmul_rn(gy, gx));
        }
      }
    }
  }
  *(float4*)(out + OUT_CENTER + p) = make_float4(bg[0], bg[1], bg[2], bg[3]);
  int4 sv4 = *(const int4*)(sem + p);
  int svv[4] = {sv4.x, sv4.y, sv4.z, sv4.w};
  int insv[4];
  bool s_any = S > 0;
#pragma unroll
  for (int j = 0; j < 4; ++j) {
    bool thing = (svv[j] >= 11 && svv[j] <= 18);
    insv[j] = (thing && s_any) ? bsg[j] : 0;
  }
  *(int4*)(ins + p) = make_int4(insv[0], insv[1], insv[2], insv[3]);
  // merged per-thread local-bin accumulation (adjacent px often share a segment)
  int curSeg = -1, aY = 0, aX = 0, aC = 0;
#pragma unroll
  for (int j = 0; j < 4; ++j) {
    if (insv[j] > 0) {
      int sg = insv[j];
      if (sg != curSeg) {
        if (curSeg >= 0) {
          atomicAdd(&lsy[curSeg], aY); atomicAdd(&lsx[curSeg], aX); atomicAdd(&lcn[curSeg], aC);
        }
        curSeg = sg; aY = 0; aX = 0; aC = 0;
      }
      aY += y; aX += x0i + j; aC += 1;
    }
  }
  if (curSeg >= 0) {
    atomicAdd(&lsy[curSeg], aY); atomicAdd(&lsx[curSeg], aX); atomicAdd(&lcn[curSeg], aC);
  }
  __syncthreads();
  for (int q = tid; q <= KC; q += 256) {
    int c = lcn[q];
    if (c) {
      int gq = b * (KC + 1) + q;
      atomicAdd(&gcn[gq], c); atomicAdd(&gsy[gq], lsy[q]); atomicAdd(&gsx[gq], lsx[q]);
    }
  }
}

// offsets (4 px/thread) + center/offset weights
__global__ __launch_bounds__(256) void k_off(
    const int* __restrict__ ins, const int* __restrict__ gsy,
    const int* __restrict__ gsx, const int* __restrict__ gcn,
    float* __restrict__ out) {
  int t = blockIdx.x * 256 + threadIdx.x;   // t < 131072
  int p = t << 2;
  int b = p >> 18, rem = p & (HWl - 1), y = rem >> 9, x0i = rem & (W_ - 1);
  int4 iv = *(const int4*)(ins + p);
  int insv[4] = {iv.x, iv.y, iv.z, iv.w};
  float oy[4], ox[4], ow[4];
  float fy = (float)y;
#pragma unroll
  for (int j = 0; j < 4; ++j) {
    if (insv[j] > 0) {
      int sg = b * (KC + 1) + insv[j];
      float c = fmaxf((float)gcn[sg], 1.0f);
      oy[j] = __fsub_rn((float)gsy[sg] / c, fy);
      ox[j] = __fsub_rn((float)gsx[sg] / c, (float)(x0i + j));
      ow[j] = 1.0f;
    } else { oy[j] = 0.0f; ox[j] = 0.0f; ow[j] = 0.0f; }
  }
  *(float4*)(out + OUT_OFF + b * 2 * HWl + rem) = make_float4(oy[0], oy[1], oy[2], oy[3]);
  *(float4*)(out + OUT_OFF + b * 2 * HWl + HWl + rem) = make_float4(ox[0], ox[1], ox[2], ox[3]);
  *(float4*)(out + OUT_CW + p) = make_float4(1.0f, 1.0f, 1.0f, 1.0f);
  *(float4*)(out + OUT_OW + p) = make_float4(ow[0], ow[1], ow[2], ow[3]);
}

// ---------------- launch ----------------
extern "C" void kernel_launch(void* const* d_in, const int* in_sizes, int n_in,
                              void* d_out, int out_size, void* d_ws, size_t ws_size,
                              hipStream_t stream) {
  const float* ctr = (const float*)d_in[0];
  const float* offs = (const float*)d_in[1];
  const int* sem = (const int*)d_in[2];
  const float* mix = (const float*)d_in[3];
  float* out = (float*)d_out;

  char* w = (char*)d_ws;
  int* gz = (int*)(w + 0);                              // gsy|gsx|gcn, 3*402 ints
  int* gsy = gz;                                        // [zeroed by k_wsum blk 0]
  int* gsx = gz + (KC + 1) * B_;
  int* gcn = gz + 2 * (KC + 1) * B_;                    // ends 4824
  int* bcount = (int*)(w + 8192);                       // 256 ints, fully rewritten
  float* cand_val = (float*)(w + 10240);
  int* cand_bid = (int*)(w + 11264);
  int* cand_cy = (int*)(w + 12288);
  int* cand_cx = (int*)(w + 13312);
  int* selected = (int*)(w + 14336);
  // keys: NBLK*1024*8 = 2 MB; ins (2 MB) OVERLAYS keys (keys dead after
  // k_sel; k_fused runs strictly later in-stream).
  unsigned long long* keys = (unsigned long long*)(w + 65536);
  int* ins = (int*)(w + 65536);

  k_nms<<<NBLK, 256, 0, stream>>>(ctr, keys, bcount);
  k_sel<<<1, 1024, 0, stream>>>(keys, bcount,
                                cand_val, cand_bid, cand_cy, cand_cx);
  k_wsum<<<KC, 256, 0, stream>>>(sem, mix, cand_val, cand_bid, cand_cy, cand_cx,
                                 selected, gz);
  k_fused<<<512, 256, 0, stream>>>(offs, sem, cand_bid, cand_cy, cand_cx, selected,
                                   ins, out, gsy, gsx, gcn);
  k_off<<<512, 256, 0, stream>>>(ins, gsy, gsx, gcn, out);
}